// Round 17
// baseline (289.612 us; speedup 1.0000x reference)
//
#include <hip/hip_runtime.h>
#include <math.h>

#define NROWS 65536
#define KEMB  2048
#define DIM   64
#define DECAYF 0.99f
#define OMDF   0.01f
#define EPSF   1e-5f

// ---- ws layout (units of 4 bytes) ----
#define WS_DW    0         // 131072 floats, TRANSPOSED dwT[64][2048] (zeroed k0, atomics k2)
#define WS_CNT   131072    // 2048 uints (zeroed k0, filled by k1 tail)
#define WS_LOSS  133120    // 1 float    (zeroed k0)
#define WS_ESQ   133632    // 2048 floats (e_sq)
#define WS_IDX   135680    // 65536 ints (argmin indices)

// ---- out layout (floats) ----
#define OUT_Q    0
#define OUT_ENC  4194304          // 65536*64
#define OUT_LOSS 138412032        // + 65536*2048
#define OUT_PERP 138412033
#define OUT_NE   138412034        // new_embedding (even offset -> float2 stores)
#define OUT_NCS  138543106        // + 2048*64

typedef float f32x4 __attribute__((ext_vector_type(4)));

// K0: zero dwT/cnt/loss, precompute e_sq. 128 blocks.
__global__ __launch_bounds__(256) void k0_prep(const float* __restrict__ E,
                                               float* __restrict__ ws) {
    int g = blockIdx.x * 256 + threadIdx.x;   // 32768 threads
    if (g == 0) ws[WS_LOSS] = 0.f;
    ((float4*)(ws + WS_DW))[g] = make_float4(0.f, 0.f, 0.f, 0.f);
    if (g < KEMB) {
        ((unsigned int*)ws)[WS_CNT + g] = 0u;
        const float4* e4 = (const float4*)(E + (size_t)g * DIM);
        float s0 = 0.f, s1 = 0.f, s2 = 0.f, s3 = 0.f;
#pragma unroll
        for (int j = 0; j < 16; j++) {
            float4 v = e4[j];
            s0 = fmaf(v.x, v.x, s0); s1 = fmaf(v.y, v.y, s1);
            s2 = fmaf(v.z, v.z, s2); s3 = fmaf(v.w, v.w, s3);
        }
        ws[WS_ESQ + g] = (s0 + s1) + (s2 + s3);
    }
}

// K1: R14 champion, untouched. SGEMM argmin, 8x16 micro-tile, 32-d halves,
// hard barriers, fused enc zero-fill + tail {idx, count, one-hot, quantized,
// loss}. 512 blocks x 256 threads, 2 blocks/CU.
__global__ __launch_bounds__(256, 2) void k1_main(const float* __restrict__ x,
                                                  const float* __restrict__ E,
                                                  float* __restrict__ ws,
                                                  float* __restrict__ out) {
    __shared__ float sxT[64 * 128];   // 32 KB  [d][row]
    __shared__ float seT[32 * 256];   // 32 KB  [d-half][swizzled code slot]
    __shared__ float sxq[256];        // x_sq partials; reused as sIdx at end

    const int t = threadIdx.x;
    const int b = blockIdx.x;
    const int tx = t & 15;            // code group (16 codes)
    const int ty = t >> 4;            // row group (8 rows)

    // ---- stage x (transposed, full D) + x_sq partials ----
    {
        const int rl = t & 127;
        const int dhi2 = t >> 7;
        const float4* x4 = (const float4*)x;
        float s0 = 0.f, s1 = 0.f, s2 = 0.f, s3 = 0.f;
#pragma unroll
        for (int i = 0; i < 8; i++) {
            int dc = dhi2 + 2 * i;
            float4 v = x4[((size_t)b * 128 + rl) * 16 + dc];
            sxT[(4 * dc + 0) * 128 + rl] = v.x;
            sxT[(4 * dc + 1) * 128 + rl] = v.y;
            sxT[(4 * dc + 2) * 128 + rl] = v.z;
            sxT[(4 * dc + 3) * 128 + rl] = v.w;
            s0 = fmaf(v.x, v.x, s0); s1 = fmaf(v.y, v.y, s1);
            s2 = fmaf(v.z, v.z, s2); s3 = fmaf(v.w, v.w, s3);
        }
        sxq[dhi2 * 128 + rl] = (s0 + s1) + (s2 + s3);
    }

    // E staging: thread t stages code c=t of the pass tile.
    // chunk (q=(c>>2)&3) of code c -> float4-slot q*16 + (c>>4).
    const int sbase = (((t >> 2) & 3) << 6) + ((t >> 4) << 2) + (t & 3);
    const float4* e4 = (const float4*)E;

    float4 pv[8];
#pragma unroll
    for (int j = 0; j < 8; j++)
        pv[j] = e4[(size_t)t * 16 + j];   // pass 0, half 0

    __syncthreads();   // sxT/sxq ready

    float xsq[8];
#pragma unroll
    for (int rr = 0; rr < 8; rr++)
        xsq[rr] = sxq[ty * 8 + rr] + sxq[128 + ty * 8 + rr];

    float best[8];
    int bidx[8];
#pragma unroll
    for (int rr = 0; rr < 8; rr++) { best[rr] = 3.4e38f; bidx[rr] = 0; }

    f32x4* __restrict__ encz = (f32x4*)(out + OUT_ENC);

    for (int pass = 0; pass < 8; pass++) {
        float acc[8][16];
#pragma unroll
        for (int rr = 0; rr < 8; rr++)
#pragma unroll
            for (int m = 0; m < 16; m++) acc[rr][m] = 0.f;

        for (int dh = 0; dh < 2; dh++) {
            if (pass + dh) __syncthreads();   // prior compute done reading seT
#pragma unroll
            for (int j = 0; j < 8; j++) {
                seT[(4 * j + 0) * 256 + sbase] = pv[j].x;
                seT[(4 * j + 1) * 256 + sbase] = pv[j].y;
                seT[(4 * j + 2) * 256 + sbase] = pv[j].z;
                seT[(4 * j + 3) * 256 + sbase] = pv[j].w;
            }
            __syncthreads();

            // prefetch next half (drains under the FMA loop)
            {
                int h = pass * 2 + dh + 1;
                if (h < 16) {
#pragma unroll
                    for (int j = 0; j < 8; j++)
                        pv[j] = e4[((size_t)((h >> 1) * 256 + t)) * 16 + (h & 1) * 8 + j];
                }
            }

            // block-local zero-fill of this block's enc rows (1/8 per pass)
            if (dh == 0) {
                f32x4 z = (f32x4)(0.f);
#pragma unroll
                for (int j = 0; j < 32; j++)
                    __builtin_nontemporal_store(z,
                        encz + (size_t)b * 65536 + pass * 8192 + j * 256 + t);
            }

            const float* xbase = sxT + dh * 32 * 128 + ty * 8;
            for (int dd = 0; dd < 32; dd++) {
                const float* sb = seT + dd * 256;
                f32x4 a0 = *(const f32x4*)(xbase + dd * 128);
                f32x4 a1 = *(const f32x4*)(xbase + dd * 128 + 4);
                f32x4 b0 = *(const f32x4*)(sb + tx * 4);
                f32x4 b1 = *(const f32x4*)(sb + 64 + tx * 4);
                f32x4 b2 = *(const f32x4*)(sb + 128 + tx * 4);
                f32x4 b3 = *(const f32x4*)(sb + 192 + tx * 4);
#pragma unroll
                for (int rr = 0; rr < 4; rr++) {
#pragma unroll
                    for (int cc = 0; cc < 4; cc++) {
                        acc[rr][cc]          = fmaf(a0[rr], b0[cc], acc[rr][cc]);
                        acc[rr][4 + cc]      = fmaf(a0[rr], b1[cc], acc[rr][4 + cc]);
                        acc[rr][8 + cc]      = fmaf(a0[rr], b2[cc], acc[rr][8 + cc]);
                        acc[rr][12 + cc]     = fmaf(a0[rr], b3[cc], acc[rr][12 + cc]);
                        acc[4 + rr][cc]      = fmaf(a1[rr], b0[cc], acc[4 + rr][cc]);
                        acc[4 + rr][4 + cc]  = fmaf(a1[rr], b1[cc], acc[4 + rr][4 + cc]);
                        acc[4 + rr][8 + cc]  = fmaf(a1[rr], b2[cc], acc[4 + rr][8 + cc]);
                        acc[4 + rr][12 + cc] = fmaf(a1[rr], b3[cc], acc[4 + rr][12 + cc]);
                    }
                }
            }
        }

        // ---- fold distances (k ascending -> first-min tie rule) ----
        const float4* esq4 = (const float4*)(ws + WS_ESQ + pass * 256 + tx * 16);
        float4 eqv0 = esq4[0], eqv1 = esq4[1], eqv2 = esq4[2], eqv3 = esq4[3];
        float eq[16] = {eqv0.x, eqv0.y, eqv0.z, eqv0.w, eqv1.x, eqv1.y, eqv1.z, eqv1.w,
                        eqv2.x, eqv2.y, eqv2.z, eqv2.w, eqv3.x, eqv3.y, eqv3.z, eqv3.w};
        const int kb = pass * 256 + tx * 16;
#pragma unroll
        for (int rr = 0; rr < 8; rr++)
#pragma unroll
            for (int m = 0; m < 16; m++) {
                float dist = fmaf(-2.f, acc[rr][m], xsq[rr]) + eq[m];
                if (dist < best[rr]) { best[rr] = dist; bidx[rr] = kb + m; }
            }
    }

    // ---- cross-tx reduce over the 16 lanes sharing rows ----
    int* sIdx = (int*)sxq;
#pragma unroll
    for (int rr = 0; rr < 8; rr++) {
        float bd = best[rr]; int bi = bidx[rr];
#pragma unroll
        for (int m = 1; m < 16; m <<= 1) {
            float od = __shfl_xor(bd, m, 64);
            int   oi = __shfl_xor(bi, m, 64);
            if (od < bd || (od == bd && oi < bi)) { bd = od; bi = oi; }
        }
        if (tx == 0) sIdx[ty * 8 + rr] = bi;
    }
    __syncthreads();   // drains sIdx writes AND this block's zero-fill stores

    // ---- tail: idx, count, one-hot, quantized gather, loss ----
    if (t < 128) {
        const int row = b * 128 + t;
        const int bi = sIdx[t];
        ((int*)ws)[WS_IDX + row] = bi;
        atomicAdd(((unsigned int*)ws) + WS_CNT + bi, 1u);
        out[OUT_ENC + (size_t)row * KEMB + bi] = 1.0f;   // zero-fill drained above
        const float4* ebb = (const float4*)(E + (size_t)bi * DIM);
        const float4* xr4 = (const float4*)(x + (size_t)row * DIM);
        float4* qo = (float4*)(out + OUT_Q + (size_t)row * DIM);
        float l0 = 0.f, l1 = 0.f, l2 = 0.f, l3 = 0.f;
#pragma unroll
        for (int j = 0; j < 16; j++) {
            float4 ev = ebb[j];
            float4 xv = xr4[j];
            qo[j] = ev;
            float d0 = ev.x - xv.x, d1 = ev.y - xv.y;
            float d2 = ev.z - xv.z, d3 = ev.w - xv.w;
            l0 = fmaf(d0, d0, l0); l1 = fmaf(d1, d1, l1);
            l2 = fmaf(d2, d2, l2); l3 = fmaf(d3, d3, l3);
        }
        float lsum = (l0 + l1) + (l2 + l3);
#pragma unroll
        for (int o = 32; o; o >>= 1) lsum += __shfl_down(lsum, o, 64);
        if ((t & 63) == 0) unsafeAtomicAdd(ws + WS_LOSS, lsum);
    }
}

// K2: d-sliced dw. 512 blocks = 16 d-groups (4 dims) x 32 row-chunks (2048
// rows). tab padded to 2056 (stride 8 mod 32 banks -> 4 dsub lanes hit 4
// distinct banks). BUGFIX R16: zero loop must cover ALL 8224 floats (was
// 8192 -> 32 stale floats fed garbage into dw, absmax 5.9). Flush skips
// exact zeros (~36% of entries, identical numerics).
__global__ __launch_bounds__(256) void k2_dwD(const float* __restrict__ x,
                                              const int* __restrict__ idxp,
                                              float* __restrict__ ws) {
    __shared__ float tab[4][2056];   // 32.1 KB, padded
    const int t = threadIdx.x;
    const int b = blockIdx.x;        // 512 blocks
    const int d0 = (b & 15) * 4;
    const int rbase = (b >> 4) * 2048;

#pragma unroll
    for (int j = 0; j < 33; j++) {
        int p = t + j * 256;
        if (p < 4 * 2056) ((float*)tab)[p] = 0.f;
    }
    __syncthreads();

    const int rt = t >> 2;        // 0..63 (row within iteration group)
    const int dsub = t & 3;       // 0..3
#pragma unroll 8
    for (int i = 0; i < 32; i++) {
        int row = rbase + i * 64 + rt;
        int code = idxp[row];                               // 4-lane broadcast
        float v = x[(size_t)row * DIM + d0 + dsub];         // 16B/row coalesced
        atomicAdd(&tab[dsub][code], v);                     // bank-conflict-free over dsub
    }
    __syncthreads();

#pragma unroll
    for (int dl = 0; dl < 4; dl++)
#pragma unroll
        for (int j2 = 0; j2 < 8; j2++) {
            int k = t + j2 * 256;
            float v = tab[dl][k];
            if (v != 0.f)
                unsafeAtomicAdd(ws + WS_DW + (size_t)(d0 + dl) * KEMB + k, v);
        }
}

// K3: stats + ncs + new_embedding (reads transposed dwT). 128 blocks.
__global__ __launch_bounds__(256) void k3_se(const float* __restrict__ cs_in,
                                             const float* __restrict__ E,
                                             const float* __restrict__ ws,
                                             float* __restrict__ out) {
    __shared__ float sred[8];
    __shared__ float sscale[16];
    __shared__ float s_n;
    const int t = threadIdx.x;
    const int b = blockIdx.x;
    const unsigned int* cnt = ((const unsigned int*)ws) + WS_CNT;

    float ln = 0.f, lent = 0.f;
#pragma unroll
    for (int j = 0; j < 8; j++) {
        int k = t * 8 + j;
        float c = (float)cnt[k];
        float ncs = DECAYF * cs_in[k] + OMDF * c;
        ln += ncs;
        float p = c * (1.0f / 65536.0f);
        lent = fmaf(p, logf(p + 1e-10f), lent);
    }
#pragma unroll
    for (int o = 32; o; o >>= 1) {
        ln += __shfl_down(ln, o, 64);
        lent += __shfl_down(lent, o, 64);
    }
    if ((t & 63) == 0) { sred[t >> 6] = ln; sred[4 + (t >> 6)] = lent; }
    __syncthreads();
    if (t == 0) {
        float n = (sred[0] + sred[1]) + (sred[2] + sred[3]);
        float ent = (sred[4] + sred[5]) + (sred[6] + sred[7]);
        s_n = n;
        if (b == 0) {
            out[OUT_LOSS] = ws[WS_LOSS] * (1.0f / 4194304.0f);
            out[OUT_PERP] = expf(-ent);
        }
    }
    __syncthreads();
    const float n = s_n;

    if (t < 16) {
        int k = b * 16 + t;
        float c = (float)cnt[k];
        float ncs = DECAYF * cs_in[k] + OMDF * c;
        out[OUT_NCS + k] = ncs;
        float cs = (ncs + EPSF) / (n + (float)KEMB * EPSF) * n;
        sscale[t] = OMDF / cs;
    }
    __syncthreads();

    // NE: thread owns code kk = b*16 + (t&15), dims d4*4..d4*4+3 (d4 = t>>4).
    const int kk = b * 16 + (t & 15);
    const int d4 = t >> 4;
    const float sc = sscale[t & 15];
    float dv0 = ws[WS_DW + (size_t)(d4 * 4 + 0) * KEMB + kk];
    float dv1 = ws[WS_DW + (size_t)(d4 * 4 + 1) * KEMB + kk];
    float dv2 = ws[WS_DW + (size_t)(d4 * 4 + 2) * KEMB + kk];
    float dv3 = ws[WS_DW + (size_t)(d4 * 4 + 3) * KEMB + kk];
    float4 e = ((const float4*)E)[kk * 16 + d4];
    float2 r0, r1;
    r0.x = fmaf(dv0, sc, DECAYF * e.x);
    r0.y = fmaf(dv1, sc, DECAYF * e.y);
    r1.x = fmaf(dv2, sc, DECAYF * e.z);
    r1.y = fmaf(dv3, sc, DECAYF * e.w);
    float2* o2 = (float2*)(out + OUT_NE);
    o2[(kk * 64 + d4 * 4) / 2 + 0] = r0;
    o2[(kk * 64 + d4 * 4) / 2 + 1] = r1;
}

extern "C" void kernel_launch(void* const* d_in, const int* in_sizes, int n_in,
                              void* d_out, int out_size, void* d_ws, size_t ws_size,
                              hipStream_t stream) {
    const float* x = (const float*)d_in[0];
    const float* E = (const float*)d_in[1];
    const float* cs = (const float*)d_in[2];
    float* out = (float*)d_out;
    float* ws = (float*)d_ws;
    const int* idxp = ((const int*)ws) + WS_IDX;

    hipLaunchKernelGGL(k0_prep, dim3(128), dim3(256), 0, stream, E, ws);
    hipLaunchKernelGGL(k1_main, dim3(512), dim3(256), 0, stream, x, E, ws, out);
    hipLaunchKernelGGL(k2_dwD, dim3(512), dim3(256), 0, stream, x, idxp, ws);
    hipLaunchKernelGGL(k3_se, dim3(128), dim3(256), 0, stream, cs, E, ws, out);
}

// Round 18
// 277.687 us; speedup vs baseline: 1.0429x; 1.0429x over previous
//
#include <hip/hip_runtime.h>
#include <math.h>

#define NROWS 65536
#define KEMB  2048
#define DIM   64
#define DECAYF 0.99f
#define OMDF   0.01f
#define EPSF   1e-5f

// ---- ws layout (units of 4 bytes) ----
#define WS_DW    0         // 131072 floats, TRANSPOSED dwT[64][2048] (zeroed k0, atomics k2)
#define WS_CNT   131072    // 2048 uints (zeroed k0, filled by k1 tail)
#define WS_LOSS  133120    // 1 float    (zeroed k0)
#define WS_ESQ   133632    // 2048 floats (e_sq)
#define WS_IDX   135680    // 65536 ints (argmin indices)

// ---- out layout (floats) ----
#define OUT_Q    0
#define OUT_ENC  4194304          // 65536*64
#define OUT_LOSS 138412032        // + 65536*2048
#define OUT_PERP 138412033
#define OUT_NE   138412034        // new_embedding (even offset -> float2 stores)
#define OUT_NCS  138543106        // + 2048*64

typedef float f32x4 __attribute__((ext_vector_type(4)));
typedef float f32x2 __attribute__((ext_vector_type(2)));

// K0: zero dwT/cnt/loss, precompute e_sq. 128 blocks.
__global__ __launch_bounds__(256) void k0_prep(const float* __restrict__ E,
                                               float* __restrict__ ws) {
    int g = blockIdx.x * 256 + threadIdx.x;   // 32768 threads
    if (g == 0) ws[WS_LOSS] = 0.f;
    ((float4*)(ws + WS_DW))[g] = make_float4(0.f, 0.f, 0.f, 0.f);
    if (g < KEMB) {
        ((unsigned int*)ws)[WS_CNT + g] = 0u;
        const float4* e4 = (const float4*)(E + (size_t)g * DIM);
        float s0 = 0.f, s1 = 0.f, s2 = 0.f, s3 = 0.f;
#pragma unroll
        for (int j = 0; j < 16; j++) {
            float4 v = e4[j];
            s0 = fmaf(v.x, v.x, s0); s1 = fmaf(v.y, v.y, s1);
            s2 = fmaf(v.z, v.z, s2); s3 = fmaf(v.w, v.w, s3);
        }
        ws[WS_ESQ + g] = (s0 + s1) + (s2 + s3);
    }
}

// K1: SGEMM argmin (R17 structure) with PACKED f32 FMA: accumulator held as
// float2 code-pairs so the inner loop emits v_pk_fma_f32 (2 MACs/issue slot)
// -> VALU issue per dd halves (128 -> 64 instructions). Fold unpacks pairs
// in ascending k (tie rule preserved). All else identical to R17 champion.
__global__ __launch_bounds__(256, 2) void k1_main(const float* __restrict__ x,
                                                  const float* __restrict__ E,
                                                  float* __restrict__ ws,
                                                  float* __restrict__ out) {
    __shared__ float sxT[64 * 128];   // 32 KB  [d][row]
    __shared__ float seT[32 * 256];   // 32 KB  [d-half][swizzled code slot]
    __shared__ float sxq[256];        // x_sq partials; reused as sIdx at end

    const int t = threadIdx.x;
    const int b = blockIdx.x;
    const int tx = t & 15;            // code group (16 codes)
    const int ty = t >> 4;            // row group (8 rows)

    // ---- stage x (transposed, full D) + x_sq partials ----
    {
        const int rl = t & 127;
        const int dhi2 = t >> 7;
        const float4* x4 = (const float4*)x;
        float s0 = 0.f, s1 = 0.f, s2 = 0.f, s3 = 0.f;
#pragma unroll
        for (int i = 0; i < 8; i++) {
            int dc = dhi2 + 2 * i;
            float4 v = x4[((size_t)b * 128 + rl) * 16 + dc];
            sxT[(4 * dc + 0) * 128 + rl] = v.x;
            sxT[(4 * dc + 1) * 128 + rl] = v.y;
            sxT[(4 * dc + 2) * 128 + rl] = v.z;
            sxT[(4 * dc + 3) * 128 + rl] = v.w;
            s0 = fmaf(v.x, v.x, s0); s1 = fmaf(v.y, v.y, s1);
            s2 = fmaf(v.z, v.z, s2); s3 = fmaf(v.w, v.w, s3);
        }
        sxq[dhi2 * 128 + rl] = (s0 + s1) + (s2 + s3);
    }

    // E staging: thread t stages code c=t of the pass tile.
    // chunk (q=(c>>2)&3) of code c -> float4-slot q*16 + (c>>4).
    const int sbase = (((t >> 2) & 3) << 6) + ((t >> 4) << 2) + (t & 3);
    const float4* e4 = (const float4*)E;

    float4 pv[8];
#pragma unroll
    for (int j = 0; j < 8; j++)
        pv[j] = e4[(size_t)t * 16 + j];   // pass 0, half 0

    __syncthreads();   // sxT/sxq ready

    float xsq[8];
#pragma unroll
    for (int rr = 0; rr < 8; rr++)
        xsq[rr] = sxq[ty * 8 + rr] + sxq[128 + ty * 8 + rr];

    float best[8];
    int bidx[8];
#pragma unroll
    for (int rr = 0; rr < 8; rr++) { best[rr] = 3.4e38f; bidx[rr] = 0; }

    f32x4* __restrict__ encz = (f32x4*)(out + OUT_ENC);

    for (int pass = 0; pass < 8; pass++) {
        f32x2 acc[8][8];                       // [row][code-pair]
#pragma unroll
        for (int rr = 0; rr < 8; rr++)
#pragma unroll
            for (int p = 0; p < 8; p++) acc[rr][p] = (f32x2)(0.f);

        for (int dh = 0; dh < 2; dh++) {
            if (pass + dh) __syncthreads();   // prior compute done reading seT
#pragma unroll
            for (int j = 0; j < 8; j++) {
                seT[(4 * j + 0) * 256 + sbase] = pv[j].x;
                seT[(4 * j + 1) * 256 + sbase] = pv[j].y;
                seT[(4 * j + 2) * 256 + sbase] = pv[j].z;
                seT[(4 * j + 3) * 256 + sbase] = pv[j].w;
            }
            __syncthreads();

            // prefetch next half (drains under the FMA loop)
            {
                int h = pass * 2 + dh + 1;
                if (h < 16) {
#pragma unroll
                    for (int j = 0; j < 8; j++)
                        pv[j] = e4[((size_t)((h >> 1) * 256 + t)) * 16 + (h & 1) * 8 + j];
                }
            }

            // block-local zero-fill of this block's enc rows (1/8 per pass)
            if (dh == 0) {
                f32x4 z = (f32x4)(0.f);
#pragma unroll
                for (int j = 0; j < 32; j++)
                    __builtin_nontemporal_store(z,
                        encz + (size_t)b * 65536 + pass * 8192 + j * 256 + t);
            }

            const float* xbase = sxT + dh * 32 * 128 + ty * 8;
            for (int dd = 0; dd < 32; dd++) {
                const float* sb = seT + dd * 256;
                f32x4 a0 = *(const f32x4*)(xbase + dd * 128);
                f32x4 a1 = *(const f32x4*)(xbase + dd * 128 + 4);
                f32x4 b0 = *(const f32x4*)(sb + tx * 4);
                f32x4 b1 = *(const f32x4*)(sb + 64 + tx * 4);
                f32x4 b2 = *(const f32x4*)(sb + 128 + tx * 4);
                f32x4 b3 = *(const f32x4*)(sb + 192 + tx * 4);
                f32x2 bp[8];
                bp[0] = __builtin_shufflevector(b0, b0, 0, 1);
                bp[1] = __builtin_shufflevector(b0, b0, 2, 3);
                bp[2] = __builtin_shufflevector(b1, b1, 0, 1);
                bp[3] = __builtin_shufflevector(b1, b1, 2, 3);
                bp[4] = __builtin_shufflevector(b2, b2, 0, 1);
                bp[5] = __builtin_shufflevector(b2, b2, 2, 3);
                bp[6] = __builtin_shufflevector(b3, b3, 0, 1);
                bp[7] = __builtin_shufflevector(b3, b3, 2, 3);
#pragma unroll
                for (int rr = 0; rr < 4; rr++) {
                    f32x2 al = (f32x2)(a0[rr]);   // splat
                    f32x2 ah = (f32x2)(a1[rr]);
#pragma unroll
                    for (int p = 0; p < 8; p++) {
                        acc[rr][p]     = __builtin_elementwise_fma(al, bp[p], acc[rr][p]);
                        acc[rr + 4][p] = __builtin_elementwise_fma(ah, bp[p], acc[rr + 4][p]);
                    }
                }
            }
        }

        // ---- fold distances (k ascending -> first-min tie rule) ----
        const float4* esq4 = (const float4*)(ws + WS_ESQ + pass * 256 + tx * 16);
        float4 eqv0 = esq4[0], eqv1 = esq4[1], eqv2 = esq4[2], eqv3 = esq4[3];
        float eq[16] = {eqv0.x, eqv0.y, eqv0.z, eqv0.w, eqv1.x, eqv1.y, eqv1.z, eqv1.w,
                        eqv2.x, eqv2.y, eqv2.z, eqv2.w, eqv3.x, eqv3.y, eqv3.z, eqv3.w};
        const int kb = pass * 256 + tx * 16;
#pragma unroll
        for (int rr = 0; rr < 8; rr++)
#pragma unroll
            for (int p = 0; p < 8; p++)
#pragma unroll
                for (int e = 0; e < 2; e++) {
                    float dist = fmaf(-2.f, acc[rr][p][e], xsq[rr]) + eq[p * 2 + e];
                    if (dist < best[rr]) { best[rr] = dist; bidx[rr] = kb + p * 2 + e; }
                }
    }

    // ---- cross-tx reduce over the 16 lanes sharing rows ----
    int* sIdx = (int*)sxq;
#pragma unroll
    for (int rr = 0; rr < 8; rr++) {
        float bd = best[rr]; int bi = bidx[rr];
#pragma unroll
        for (int m = 1; m < 16; m <<= 1) {
            float od = __shfl_xor(bd, m, 64);
            int   oi = __shfl_xor(bi, m, 64);
            if (od < bd || (od == bd && oi < bi)) { bd = od; bi = oi; }
        }
        if (tx == 0) sIdx[ty * 8 + rr] = bi;
    }
    __syncthreads();   // drains sIdx writes AND this block's zero-fill stores

    // ---- tail: idx, count, one-hot, quantized gather, loss ----
    if (t < 128) {
        const int row = b * 128 + t;
        const int bi = sIdx[t];
        ((int*)ws)[WS_IDX + row] = bi;
        atomicAdd(((unsigned int*)ws) + WS_CNT + bi, 1u);
        out[OUT_ENC + (size_t)row * KEMB + bi] = 1.0f;   // zero-fill drained above
        const float4* ebb = (const float4*)(E + (size_t)bi * DIM);
        const float4* xr4 = (const float4*)(x + (size_t)row * DIM);
        float4* qo = (float4*)(out + OUT_Q + (size_t)row * DIM);
        float l0 = 0.f, l1 = 0.f, l2 = 0.f, l3 = 0.f;
#pragma unroll
        for (int j = 0; j < 16; j++) {
            float4 ev = ebb[j];
            float4 xv = xr4[j];
            qo[j] = ev;
            float d0 = ev.x - xv.x, d1 = ev.y - xv.y;
            float d2 = ev.z - xv.z, d3 = ev.w - xv.w;
            l0 = fmaf(d0, d0, l0); l1 = fmaf(d1, d1, l1);
            l2 = fmaf(d2, d2, l2); l3 = fmaf(d3, d3, l3);
        }
        float lsum = (l0 + l1) + (l2 + l3);
#pragma unroll
        for (int o = 32; o; o >>= 1) lsum += __shfl_down(lsum, o, 64);
        if ((t & 63) == 0) unsafeAtomicAdd(ws + WS_LOSS, lsum);
    }
}

// K2: d-sliced dw. 512 blocks = 16 d-groups (4 dims) x 32 row-chunks (2048
// rows). tab padded to 2056 (stride 8 mod 32 banks -> 4 dsub lanes hit 4
// distinct banks). Zero loop covers all 8224 floats (R16 bugfix). Flush
// skips exact zeros (identical numerics).
__global__ __launch_bounds__(256) void k2_dwD(const float* __restrict__ x,
                                              const int* __restrict__ idxp,
                                              float* __restrict__ ws) {
    __shared__ float tab[4][2056];   // 32.1 KB, padded
    const int t = threadIdx.x;
    const int b = blockIdx.x;        // 512 blocks
    const int d0 = (b & 15) * 4;
    const int rbase = (b >> 4) * 2048;

#pragma unroll
    for (int j = 0; j < 33; j++) {
        int p = t + j * 256;
        if (p < 4 * 2056) ((float*)tab)[p] = 0.f;
    }
    __syncthreads();

    const int rt = t >> 2;        // 0..63 (row within iteration group)
    const int dsub = t & 3;       // 0..3
#pragma unroll 8
    for (int i = 0; i < 32; i++) {
        int row = rbase + i * 64 + rt;
        int code = idxp[row];                               // 4-lane broadcast
        float v = x[(size_t)row * DIM + d0 + dsub];         // 16B/row coalesced
        atomicAdd(&tab[dsub][code], v);                     // bank-conflict-free over dsub
    }
    __syncthreads();

#pragma unroll
    for (int dl = 0; dl < 4; dl++)
#pragma unroll
        for (int j2 = 0; j2 < 8; j2++) {
            int k = t + j2 * 256;
            float v = tab[dl][k];
            if (v != 0.f)
                unsafeAtomicAdd(ws + WS_DW + (size_t)(d0 + dl) * KEMB + k, v);
        }
}

// K3: stats + ncs + new_embedding (reads transposed dwT). 128 blocks.
__global__ __launch_bounds__(256) void k3_se(const float* __restrict__ cs_in,
                                             const float* __restrict__ E,
                                             const float* __restrict__ ws,
                                             float* __restrict__ out) {
    __shared__ float sred[8];
    __shared__ float sscale[16];
    __shared__ float s_n;
    const int t = threadIdx.x;
    const int b = blockIdx.x;
    const unsigned int* cnt = ((const unsigned int*)ws) + WS_CNT;

    float ln = 0.f, lent = 0.f;
#pragma unroll
    for (int j = 0; j < 8; j++) {
        int k = t * 8 + j;
        float c = (float)cnt[k];
        float ncs = DECAYF * cs_in[k] + OMDF * c;
        ln += ncs;
        float p = c * (1.0f / 65536.0f);
        lent = fmaf(p, logf(p + 1e-10f), lent);
    }
#pragma unroll
    for (int o = 32; o; o >>= 1) {
        ln += __shfl_down(ln, o, 64);
        lent += __shfl_down(lent, o, 64);
    }
    if ((t & 63) == 0) { sred[t >> 6] = ln; sred[4 + (t >> 6)] = lent; }
    __syncthreads();
    if (t == 0) {
        float n = (sred[0] + sred[1]) + (sred[2] + sred[3]);
        float ent = (sred[4] + sred[5]) + (sred[6] + sred[7]);
        s_n = n;
        if (b == 0) {
            out[OUT_LOSS] = ws[WS_LOSS] * (1.0f / 4194304.0f);
            out[OUT_PERP] = expf(-ent);
        }
    }
    __syncthreads();
    const float n = s_n;

    if (t < 16) {
        int k = b * 16 + t;
        float c = (float)cnt[k];
        float ncs = DECAYF * cs_in[k] + OMDF * c;
        out[OUT_NCS + k] = ncs;
        float cs = (ncs + EPSF) / (n + (float)KEMB * EPSF) * n;
        sscale[t] = OMDF / cs;
    }
    __syncthreads();

    // NE: thread owns code kk = b*16 + (t&15), dims d4*4..d4*4+3 (d4 = t>>4).
    const int kk = b * 16 + (t & 15);
    const int d4 = t >> 4;
    const float sc = sscale[t & 15];
    float dv0 = ws[WS_DW + (size_t)(d4 * 4 + 0) * KEMB + kk];
    float dv1 = ws[WS_DW + (size_t)(d4 * 4 + 1) * KEMB + kk];
    float dv2 = ws[WS_DW + (size_t)(d4 * 4 + 2) * KEMB + kk];
    float dv3 = ws[WS_DW + (size_t)(d4 * 4 + 3) * KEMB + kk];
    float4 e = ((const float4*)E)[kk * 16 + d4];
    float2 r0, r1;
    r0.x = fmaf(dv0, sc, DECAYF * e.x);
    r0.y = fmaf(dv1, sc, DECAYF * e.y);
    r1.x = fmaf(dv2, sc, DECAYF * e.z);
    r1.y = fmaf(dv3, sc, DECAYF * e.w);
    float2* o2 = (float2*)(out + OUT_NE);
    o2[(kk * 64 + d4 * 4) / 2 + 0] = r0;
    o2[(kk * 64 + d4 * 4) / 2 + 1] = r1;
}

extern "C" void kernel_launch(void* const* d_in, const int* in_sizes, int n_in,
                              void* d_out, int out_size, void* d_ws, size_t ws_size,
                              hipStream_t stream) {
    const float* x = (const float*)d_in[0];
    const float* E = (const float*)d_in[1];
    const float* cs = (const float*)d_in[2];
    float* out = (float*)d_out;
    float* ws = (float*)d_ws;
    const int* idxp = ((const int*)ws) + WS_IDX;

    hipLaunchKernelGGL(k0_prep, dim3(128), dim3(256), 0, stream, E, ws);
    hipLaunchKernelGGL(k1_main, dim3(512), dim3(256), 0, stream, x, E, ws, out);
    hipLaunchKernelGGL(k2_dwD, dim3(512), dim3(256), 0, stream, x, idxp, ws);
    hipLaunchKernelGGL(k3_se, dim3(128), dim3(256), 0, stream, cs, E, ws, out);
}

// Round 19
// 276.929 us; speedup vs baseline: 1.0458x; 1.0027x over previous
//
#include <hip/hip_runtime.h>
#include <math.h>

#define NROWS 65536
#define KEMB  2048
#define DIM   64
#define DECAYF 0.99f
#define OMDF   0.01f
#define EPSF   1e-5f

// ---- ws layout (units of 4 bytes) ----
#define WS_DW    0         // 131072 floats, TRANSPOSED dwT[64][2048] (zeroed k0, atomics k2)
#define WS_CNT   131072    // 2048 uints (zeroed k0, filled by k2 histogram)
#define WS_LOSS  133120    // 1 float    (zeroed k0)
#define WS_ESQ   133632    // 2048 floats (e_sq)
#define WS_IDX   135680    // 65536 ints (argmin indices)

// ---- out layout (floats) ----
#define OUT_Q    0
#define OUT_ENC  4194304          // 65536*64
#define OUT_LOSS 138412032        // + 65536*2048
#define OUT_PERP 138412033
#define OUT_NE   138412034        // new_embedding (even offset -> float2 stores)
#define OUT_NCS  138543106        // + 2048*64

typedef float f32x4 __attribute__((ext_vector_type(4)));
typedef float f32x2 __attribute__((ext_vector_type(2)));

// K0: zero dwT/cnt/loss, precompute e_sq. 128 blocks.
__global__ __launch_bounds__(256) void k0_prep(const float* __restrict__ E,
                                               float* __restrict__ ws) {
    int g = blockIdx.x * 256 + threadIdx.x;   // 32768 threads
    if (g == 0) ws[WS_LOSS] = 0.f;
    ((float4*)(ws + WS_DW))[g] = make_float4(0.f, 0.f, 0.f, 0.f);
    if (g < KEMB) {
        ((unsigned int*)ws)[WS_CNT + g] = 0u;
        const float4* e4 = (const float4*)(E + (size_t)g * DIM);
        float s0 = 0.f, s1 = 0.f, s2 = 0.f, s3 = 0.f;
#pragma unroll
        for (int j = 0; j < 16; j++) {
            float4 v = e4[j];
            s0 = fmaf(v.x, v.x, s0); s1 = fmaf(v.y, v.y, s1);
            s2 = fmaf(v.z, v.z, s2); s3 = fmaf(v.w, v.w, s3);
        }
        ws[WS_ESQ + g] = (s0 + s1) + (s2 + s3);
    }
}

// K1: SGEMM argmin, packed v_pk_fma_f32 accumulator (R18 champion). Tail no
// longer does the contended cnt atomic (migrated to k2's histogram).
__global__ __launch_bounds__(256, 2) void k1_main(const float* __restrict__ x,
                                                  const float* __restrict__ E,
                                                  float* __restrict__ ws,
                                                  float* __restrict__ out) {
    __shared__ float sxT[64 * 128];   // 32 KB  [d][row]
    __shared__ float seT[32 * 256];   // 32 KB  [d-half][swizzled code slot]
    __shared__ float sxq[256];        // x_sq partials; reused as sIdx at end

    const int t = threadIdx.x;
    const int b = blockIdx.x;
    const int tx = t & 15;            // code group (16 codes)
    const int ty = t >> 4;            // row group (8 rows)

    // ---- stage x (transposed, full D) + x_sq partials ----
    {
        const int rl = t & 127;
        const int dhi2 = t >> 7;
        const float4* x4 = (const float4*)x;
        float s0 = 0.f, s1 = 0.f, s2 = 0.f, s3 = 0.f;
#pragma unroll
        for (int i = 0; i < 8; i++) {
            int dc = dhi2 + 2 * i;
            float4 v = x4[((size_t)b * 128 + rl) * 16 + dc];
            sxT[(4 * dc + 0) * 128 + rl] = v.x;
            sxT[(4 * dc + 1) * 128 + rl] = v.y;
            sxT[(4 * dc + 2) * 128 + rl] = v.z;
            sxT[(4 * dc + 3) * 128 + rl] = v.w;
            s0 = fmaf(v.x, v.x, s0); s1 = fmaf(v.y, v.y, s1);
            s2 = fmaf(v.z, v.z, s2); s3 = fmaf(v.w, v.w, s3);
        }
        sxq[dhi2 * 128 + rl] = (s0 + s1) + (s2 + s3);
    }

    // E staging: thread t stages code c=t of the pass tile.
    // chunk (q=(c>>2)&3) of code c -> float4-slot q*16 + (c>>4).
    const int sbase = (((t >> 2) & 3) << 6) + ((t >> 4) << 2) + (t & 3);
    const float4* e4 = (const float4*)E;

    float4 pv[8];
#pragma unroll
    for (int j = 0; j < 8; j++)
        pv[j] = e4[(size_t)t * 16 + j];   // pass 0, half 0

    __syncthreads();   // sxT/sxq ready

    float xsq[8];
#pragma unroll
    for (int rr = 0; rr < 8; rr++)
        xsq[rr] = sxq[ty * 8 + rr] + sxq[128 + ty * 8 + rr];

    float best[8];
    int bidx[8];
#pragma unroll
    for (int rr = 0; rr < 8; rr++) { best[rr] = 3.4e38f; bidx[rr] = 0; }

    f32x4* __restrict__ encz = (f32x4*)(out + OUT_ENC);

    for (int pass = 0; pass < 8; pass++) {
        f32x2 acc[8][8];                       // [row][code-pair]
#pragma unroll
        for (int rr = 0; rr < 8; rr++)
#pragma unroll
            for (int p = 0; p < 8; p++) acc[rr][p] = (f32x2)(0.f);

        for (int dh = 0; dh < 2; dh++) {
            if (pass + dh) __syncthreads();   // prior compute done reading seT
#pragma unroll
            for (int j = 0; j < 8; j++) {
                seT[(4 * j + 0) * 256 + sbase] = pv[j].x;
                seT[(4 * j + 1) * 256 + sbase] = pv[j].y;
                seT[(4 * j + 2) * 256 + sbase] = pv[j].z;
                seT[(4 * j + 3) * 256 + sbase] = pv[j].w;
            }
            __syncthreads();

            // prefetch next half (drains under the FMA loop)
            {
                int h = pass * 2 + dh + 1;
                if (h < 16) {
#pragma unroll
                    for (int j = 0; j < 8; j++)
                        pv[j] = e4[((size_t)((h >> 1) * 256 + t)) * 16 + (h & 1) * 8 + j];
                }
            }

            // block-local zero-fill of this block's enc rows (1/8 per pass)
            if (dh == 0) {
                f32x4 z = (f32x4)(0.f);
#pragma unroll
                for (int j = 0; j < 32; j++)
                    __builtin_nontemporal_store(z,
                        encz + (size_t)b * 65536 + pass * 8192 + j * 256 + t);
            }

            const float* xbase = sxT + dh * 32 * 128 + ty * 8;
            for (int dd = 0; dd < 32; dd++) {
                const float* sb = seT + dd * 256;
                f32x4 a0 = *(const f32x4*)(xbase + dd * 128);
                f32x4 a1 = *(const f32x4*)(xbase + dd * 128 + 4);
                f32x4 b0 = *(const f32x4*)(sb + tx * 4);
                f32x4 b1 = *(const f32x4*)(sb + 64 + tx * 4);
                f32x4 b2 = *(const f32x4*)(sb + 128 + tx * 4);
                f32x4 b3 = *(const f32x4*)(sb + 192 + tx * 4);
                f32x2 bp[8];
                bp[0] = __builtin_shufflevector(b0, b0, 0, 1);
                bp[1] = __builtin_shufflevector(b0, b0, 2, 3);
                bp[2] = __builtin_shufflevector(b1, b1, 0, 1);
                bp[3] = __builtin_shufflevector(b1, b1, 2, 3);
                bp[4] = __builtin_shufflevector(b2, b2, 0, 1);
                bp[5] = __builtin_shufflevector(b2, b2, 2, 3);
                bp[6] = __builtin_shufflevector(b3, b3, 0, 1);
                bp[7] = __builtin_shufflevector(b3, b3, 2, 3);
#pragma unroll
                for (int rr = 0; rr < 4; rr++) {
                    f32x2 al = (f32x2)(a0[rr]);   // splat
                    f32x2 ah = (f32x2)(a1[rr]);
#pragma unroll
                    for (int p = 0; p < 8; p++) {
                        acc[rr][p]     = __builtin_elementwise_fma(al, bp[p], acc[rr][p]);
                        acc[rr + 4][p] = __builtin_elementwise_fma(ah, bp[p], acc[rr + 4][p]);
                    }
                }
            }
        }

        // ---- fold distances (k ascending -> first-min tie rule) ----
        const float4* esq4 = (const float4*)(ws + WS_ESQ + pass * 256 + tx * 16);
        float4 eqv0 = esq4[0], eqv1 = esq4[1], eqv2 = esq4[2], eqv3 = esq4[3];
        float eq[16] = {eqv0.x, eqv0.y, eqv0.z, eqv0.w, eqv1.x, eqv1.y, eqv1.z, eqv1.w,
                        eqv2.x, eqv2.y, eqv2.z, eqv2.w, eqv3.x, eqv3.y, eqv3.z, eqv3.w};
        const int kb = pass * 256 + tx * 16;
#pragma unroll
        for (int rr = 0; rr < 8; rr++)
#pragma unroll
            for (int p = 0; p < 8; p++)
#pragma unroll
                for (int e = 0; e < 2; e++) {
                    float dist = fmaf(-2.f, acc[rr][p][e], xsq[rr]) + eq[p * 2 + e];
                    if (dist < best[rr]) { best[rr] = dist; bidx[rr] = kb + p * 2 + e; }
                }
    }

    // ---- cross-tx reduce over the 16 lanes sharing rows ----
    int* sIdx = (int*)sxq;
#pragma unroll
    for (int rr = 0; rr < 8; rr++) {
        float bd = best[rr]; int bi = bidx[rr];
#pragma unroll
        for (int m = 1; m < 16; m <<= 1) {
            float od = __shfl_xor(bd, m, 64);
            int   oi = __shfl_xor(bi, m, 64);
            if (od < bd || (od == bd && oi < bi)) { bd = od; bi = oi; }
        }
        if (tx == 0) sIdx[ty * 8 + rr] = bi;
    }
    __syncthreads();   // drains sIdx writes AND this block's zero-fill stores

    // ---- tail: idx, one-hot, quantized gather, loss (cnt moved to k2) ----
    if (t < 128) {
        const int row = b * 128 + t;
        const int bi = sIdx[t];
        ((int*)ws)[WS_IDX + row] = bi;
        out[OUT_ENC + (size_t)row * KEMB + bi] = 1.0f;   // zero-fill drained above
        const float4* ebb = (const float4*)(E + (size_t)bi * DIM);
        const float4* xr4 = (const float4*)(x + (size_t)row * DIM);
        float4* qo = (float4*)(out + OUT_Q + (size_t)row * DIM);
        float l0 = 0.f, l1 = 0.f, l2 = 0.f, l3 = 0.f;
#pragma unroll
        for (int j = 0; j < 16; j++) {
            float4 ev = ebb[j];
            float4 xv = xr4[j];
            qo[j] = ev;
            float d0 = ev.x - xv.x, d1 = ev.y - xv.y;
            float d2 = ev.z - xv.z, d3 = ev.w - xv.w;
            l0 = fmaf(d0, d0, l0); l1 = fmaf(d1, d1, l1);
            l2 = fmaf(d2, d2, l2); l3 = fmaf(d3, d3, l3);
        }
        float lsum = (l0 + l1) + (l2 + l3);
#pragma unroll
        for (int o = 32; o; o >>= 1) lsum += __shfl_down(lsum, o, 64);
        if ((t & 63) == 0) unsafeAtomicAdd(ws + WS_LOSS, lsum);
    }
}

// K2: d-sliced dw + (d-group-0 blocks) code histogram. 512 blocks = 16
// d-groups (4 dims) x 32 row-chunks (2048 rows). tab padded to 2056 (4 dsub
// lanes hit 4 distinct banks). Flush skips exact zeros. Counting blocks
// flush contiguous (coalescable) atomic bursts instead of k1's 64-random-
// address contended adds.
__global__ __launch_bounds__(256) void k2_dwD(const float* __restrict__ x,
                                              const int* __restrict__ idxp,
                                              float* __restrict__ ws) {
    __shared__ float tab[4][2056];         // 32.1 KB, padded
    __shared__ unsigned int htab[KEMB];    // 8 KB (used when b&15==0)
    const int t = threadIdx.x;
    const int b = blockIdx.x;              // 512 blocks
    const int d0 = (b & 15) * 4;
    const int rbase = (b >> 4) * 2048;
    const bool counting = (b & 15) == 0;

#pragma unroll
    for (int j = 0; j < 33; j++) {
        int p = t + j * 256;
        if (p < 4 * 2056) ((float*)tab)[p] = 0.f;
    }
    if (counting) {
#pragma unroll
        for (int j = 0; j < 8; j++) htab[t + j * 256] = 0u;
    }
    __syncthreads();

    const int rt = t >> 2;        // 0..63 (row within iteration group)
    const int dsub = t & 3;       // 0..3
#pragma unroll 8
    for (int i = 0; i < 32; i++) {
        int row = rbase + i * 64 + rt;
        int code = idxp[row];                               // 4-lane broadcast
        float v = x[(size_t)row * DIM + d0 + dsub];         // 16B/row coalesced
        atomicAdd(&tab[dsub][code], v);                     // bank-conflict-free over dsub
        if (counting && dsub == 0) atomicAdd(&htab[code], 1u);
    }
    __syncthreads();

#pragma unroll
    for (int dl = 0; dl < 4; dl++)
#pragma unroll
        for (int j2 = 0; j2 < 8; j2++) {
            int k = t + j2 * 256;
            float v = tab[dl][k];
            if (v != 0.f)
                unsafeAtomicAdd(ws + WS_DW + (size_t)(d0 + dl) * KEMB + k, v);
        }
    if (counting) {
#pragma unroll
        for (int j = 0; j < 8; j++) {
            int k = t + j * 256;
            unsigned int v = htab[k];
            if (v) atomicAdd(((unsigned int*)ws) + WS_CNT + k, v);
        }
    }
}

// K3: stats + ncs + new_embedding (reads transposed dwT). 128 blocks.
__global__ __launch_bounds__(256) void k3_se(const float* __restrict__ cs_in,
                                             const float* __restrict__ E,
                                             const float* __restrict__ ws,
                                             float* __restrict__ out) {
    __shared__ float sred[8];
    __shared__ float sscale[16];
    __shared__ float s_n;
    const int t = threadIdx.x;
    const int b = blockIdx.x;
    const unsigned int* cnt = ((const unsigned int*)ws) + WS_CNT;

    float ln = 0.f, lent = 0.f;
#pragma unroll
    for (int j = 0; j < 8; j++) {
        int k = t * 8 + j;
        float c = (float)cnt[k];
        float ncs = DECAYF * cs_in[k] + OMDF * c;
        ln += ncs;
        float p = c * (1.0f / 65536.0f);
        lent = fmaf(p, logf(p + 1e-10f), lent);
    }
#pragma unroll
    for (int o = 32; o; o >>= 1) {
        ln += __shfl_down(ln, o, 64);
        lent += __shfl_down(lent, o, 64);
    }
    if ((t & 63) == 0) { sred[t >> 6] = ln; sred[4 + (t >> 6)] = lent; }
    __syncthreads();
    if (t == 0) {
        float n = (sred[0] + sred[1]) + (sred[2] + sred[3]);
        float ent = (sred[4] + sred[5]) + (sred[6] + sred[7]);
        s_n = n;
        if (b == 0) {
            out[OUT_LOSS] = ws[WS_LOSS] * (1.0f / 4194304.0f);
            out[OUT_PERP] = expf(-ent);
        }
    }
    __syncthreads();
    const float n = s_n;

    if (t < 16) {
        int k = b * 16 + t;
        float c = (float)cnt[k];
        float ncs = DECAYF * cs_in[k] + OMDF * c;
        out[OUT_NCS + k] = ncs;
        float cs = (ncs + EPSF) / (n + (float)KEMB * EPSF) * n;
        sscale[t] = OMDF / cs;
    }
    __syncthreads();

    // NE: thread owns code kk = b*16 + (t&15), dims d4*4..d4*4+3 (d4 = t>>4).
    const int kk = b * 16 + (t & 15);
    const int d4 = t >> 4;
    const float sc = sscale[t & 15];
    float dv0 = ws[WS_DW + (size_t)(d4 * 4 + 0) * KEMB + kk];
    float dv1 = ws[WS_DW + (size_t)(d4 * 4 + 1) * KEMB + kk];
    float dv2 = ws[WS_DW + (size_t)(d4 * 4 + 2) * KEMB + kk];
    float dv3 = ws[WS_DW + (size_t)(d4 * 4 + 3) * KEMB + kk];
    float4 e = ((const float4*)E)[kk * 16 + d4];
    float2 r0, r1;
    r0.x = fmaf(dv0, sc, DECAYF * e.x);
    r0.y = fmaf(dv1, sc, DECAYF * e.y);
    r1.x = fmaf(dv2, sc, DECAYF * e.z);
    r1.y = fmaf(dv3, sc, DECAYF * e.w);
    float2* o2 = (float2*)(out + OUT_NE);
    o2[(kk * 64 + d4 * 4) / 2 + 0] = r0;
    o2[(kk * 64 + d4 * 4) / 2 + 1] = r1;
}

extern "C" void kernel_launch(void* const* d_in, const int* in_sizes, int n_in,
                              void* d_out, int out_size, void* d_ws, size_t ws_size,
                              hipStream_t stream) {
    const float* x = (const float*)d_in[0];
    const float* E = (const float*)d_in[1];
    const float* cs = (const float*)d_in[2];
    float* out = (float*)d_out;
    float* ws = (float*)d_ws;
    const int* idxp = ((const int*)ws) + WS_IDX;

    hipLaunchKernelGGL(k0_prep, dim3(128), dim3(256), 0, stream, E, ws);
    hipLaunchKernelGGL(k1_main, dim3(512), dim3(256), 0, stream, x, E, ws, out);
    hipLaunchKernelGGL(k2_dwD, dim3(512), dim3(256), 0, stream, x, idxp, ws);
    hipLaunchKernelGGL(k3_se, dim3(128), dim3(256), 0, stream, cs, E, ws, out);
}

// Round 20
// 275.794 us; speedup vs baseline: 1.0501x; 1.0041x over previous
//
#include <hip/hip_runtime.h>
#include <math.h>

#define NROWS 65536
#define KEMB  2048
#define DIM   64
#define DECAYF 0.99f
#define OMDF   0.01f
#define EPSF   1e-5f

// ---- ws layout (units of 4 bytes) ----
#define WS_DW    0         // 131072 floats, TRANSPOSED dwT[64][2048] (zeroed k0, atomics k2)
#define WS_CNT   131072    // 2048 uints (zeroed k0, filled by k2 histogram)
#define WS_LOSS  133120    // 1 float    (zeroed k0)
#define WS_ESQ   133632    // 2048 floats (e_sq)
#define WS_IDX   135680    // 65536 ints (argmin indices)

// ---- out layout (floats) ----
#define OUT_Q    0
#define OUT_ENC  4194304          // 65536*64
#define OUT_LOSS 138412032        // + 65536*2048
#define OUT_PERP 138412033
#define OUT_NE   138412034        // new_embedding (even offset -> float2 stores)
#define OUT_NCS  138543106        // + 2048*64

typedef float f32x4 __attribute__((ext_vector_type(4)));
typedef float f32x2 __attribute__((ext_vector_type(2)));

// K0: zero dwT/cnt/loss, precompute e_sq. 128 blocks.
__global__ __launch_bounds__(256) void k0_prep(const float* __restrict__ E,
                                               float* __restrict__ ws) {
    int g = blockIdx.x * 256 + threadIdx.x;   // 32768 threads
    if (g == 0) ws[WS_LOSS] = 0.f;
    ((float4*)(ws + WS_DW))[g] = make_float4(0.f, 0.f, 0.f, 0.f);
    if (g < KEMB) {
        ((unsigned int*)ws)[WS_CNT + g] = 0u;
        const float4* e4 = (const float4*)(E + (size_t)g * DIM);
        float s0 = 0.f, s1 = 0.f, s2 = 0.f, s3 = 0.f;
#pragma unroll
        for (int j = 0; j < 16; j++) {
            float4 v = e4[j];
            s0 = fmaf(v.x, v.x, s0); s1 = fmaf(v.y, v.y, s1);
            s2 = fmaf(v.z, v.z, s2); s3 = fmaf(v.w, v.w, s3);
        }
        ws[WS_ESQ + g] = (s0 + s1) + (s2 + s3);
    }
}

// K1: SGEMM argmin, packed FMA + DOUBLE-BUFFERED seT (2 x 16KB quarters).
// Per stage: write buf^1 (next stage) DURING compute on buf, ONE barrier at
// stage end (proves next-buffer-written AND current-buffer-drained). Removes
// the exposed barrier->write->barrier staging window of the R18 champion.
__global__ __launch_bounds__(256, 2) void k1_main(const float* __restrict__ x,
                                                  const float* __restrict__ E,
                                                  float* __restrict__ ws,
                                                  float* __restrict__ out) {
    __shared__ float sxT[64 * 128];     // 32 KB  [d][row]
    __shared__ float seT[2][16 * 256];  // 2 x 16 KB [d-quarter][swizzled slot]
    __shared__ float sxq[256];          // x_sq partials; reused as sIdx at end

    const int t = threadIdx.x;
    const int b = blockIdx.x;
    const int tx = t & 15;            // code group (16 codes)
    const int ty = t >> 4;            // row group (8 rows)

    // ---- stage x (transposed, full D) + x_sq partials ----
    {
        const int rl = t & 127;
        const int dhi2 = t >> 7;
        const float4* x4 = (const float4*)x;
        float s0 = 0.f, s1 = 0.f, s2 = 0.f, s3 = 0.f;
#pragma unroll
        for (int i = 0; i < 8; i++) {
            int dc = dhi2 + 2 * i;
            float4 v = x4[((size_t)b * 128 + rl) * 16 + dc];
            sxT[(4 * dc + 0) * 128 + rl] = v.x;
            sxT[(4 * dc + 1) * 128 + rl] = v.y;
            sxT[(4 * dc + 2) * 128 + rl] = v.z;
            sxT[(4 * dc + 3) * 128 + rl] = v.w;
            s0 = fmaf(v.x, v.x, s0); s1 = fmaf(v.y, v.y, s1);
            s2 = fmaf(v.z, v.z, s2); s3 = fmaf(v.w, v.w, s3);
        }
        sxq[dhi2 * 128 + rl] = (s0 + s1) + (s2 + s3);
    }

    // E staging: thread t stages code c=t of the pass tile.
    // chunk (q2=(c>>2)&3) of code c -> float4-slot q2*16 + (c>>4).
    const int sbase = (((t >> 2) & 3) << 6) + ((t >> 4) << 2) + (t & 3);
    const float4* e4 = (const float4*)E;

    float4 pv[4];
    // stage 0 (pass 0, quarter 0, dims 0..15) -> write buf0 directly
#pragma unroll
    for (int j = 0; j < 4; j++)
        pv[j] = e4[(size_t)t * 16 + j];
#pragma unroll
    for (int j = 0; j < 4; j++) {
        seT[0][(4 * j + 0) * 256 + sbase] = pv[j].x;
        seT[0][(4 * j + 1) * 256 + sbase] = pv[j].y;
        seT[0][(4 * j + 2) * 256 + sbase] = pv[j].z;
        seT[0][(4 * j + 3) * 256 + sbase] = pv[j].w;
    }
    // preload stage 1 (pass 0, quarter 1) into pv
#pragma unroll
    for (int j = 0; j < 4; j++)
        pv[j] = e4[(size_t)t * 16 + 4 + j];

    __syncthreads();   // sxT/sxq/buf0 ready

    float xsq[8];
#pragma unroll
    for (int rr = 0; rr < 8; rr++)
        xsq[rr] = sxq[ty * 8 + rr] + sxq[128 + ty * 8 + rr];

    float best[8];
    int bidx[8];
#pragma unroll
    for (int rr = 0; rr < 8; rr++) { best[rr] = 3.4e38f; bidx[rr] = 0; }

    f32x4* __restrict__ encz = (f32x4*)(out + OUT_ENC);

    for (int pass = 0; pass < 8; pass++) {
        f32x2 acc[8][8];                       // [row][code-pair]
#pragma unroll
        for (int rr = 0; rr < 8; rr++)
#pragma unroll
            for (int p = 0; p < 8; p++) acc[rr][p] = (f32x2)(0.f);

        for (int q = 0; q < 4; q++) {
            const int s = pass * 4 + q;
            const int buf = s & 1;

            // write stage s+1 into the other buffer (overlaps compute below;
            // drained by the end-of-stage barrier's lgkmcnt)
            if (s < 31) {
#pragma unroll
                for (int j = 0; j < 4; j++) {
                    seT[buf ^ 1][(4 * j + 0) * 256 + sbase] = pv[j].x;
                    seT[buf ^ 1][(4 * j + 1) * 256 + sbase] = pv[j].y;
                    seT[buf ^ 1][(4 * j + 2) * 256 + sbase] = pv[j].z;
                    seT[buf ^ 1][(4 * j + 3) * 256 + sbase] = pv[j].w;
                }
            }
            // prefetch stage s+2 from global (drains under the FMA loop)
            if (s < 30) {
                int h = s + 2;
#pragma unroll
                for (int j = 0; j < 4; j++)
                    pv[j] = e4[(size_t)((h >> 2) * 256 + t) * 16 + (h & 3) * 4 + j];
            }

            // zero-fill 8 f32x4 of this block's enc rows per stage
            {
                f32x4 z = (f32x4)(0.f);
#pragma unroll
                for (int j = 0; j < 8; j++)
                    __builtin_nontemporal_store(z,
                        encz + (size_t)b * 65536 + s * 2048 + j * 256 + t);
            }

            // ---- compute 16 dd on buf ----
            const float* xbase = sxT + (q * 16) * 128 + ty * 8;
            const float* sbuf = seT[buf];
            for (int dd = 0; dd < 16; dd++) {
                const float* sb = sbuf + dd * 256;
                f32x4 a0 = *(const f32x4*)(xbase + dd * 128);
                f32x4 a1 = *(const f32x4*)(xbase + dd * 128 + 4);
                f32x4 b0 = *(const f32x4*)(sb + tx * 4);
                f32x4 b1 = *(const f32x4*)(sb + 64 + tx * 4);
                f32x4 b2 = *(const f32x4*)(sb + 128 + tx * 4);
                f32x4 b3 = *(const f32x4*)(sb + 192 + tx * 4);
                f32x2 bp[8];
                bp[0] = __builtin_shufflevector(b0, b0, 0, 1);
                bp[1] = __builtin_shufflevector(b0, b0, 2, 3);
                bp[2] = __builtin_shufflevector(b1, b1, 0, 1);
                bp[3] = __builtin_shufflevector(b1, b1, 2, 3);
                bp[4] = __builtin_shufflevector(b2, b2, 0, 1);
                bp[5] = __builtin_shufflevector(b2, b2, 2, 3);
                bp[6] = __builtin_shufflevector(b3, b3, 0, 1);
                bp[7] = __builtin_shufflevector(b3, b3, 2, 3);
#pragma unroll
                for (int rr = 0; rr < 4; rr++) {
                    f32x2 al = (f32x2)(a0[rr]);   // splat
                    f32x2 ah = (f32x2)(a1[rr]);
#pragma unroll
                    for (int p = 0; p < 8; p++) {
                        acc[rr][p]     = __builtin_elementwise_fma(al, bp[p], acc[rr][p]);
                        acc[rr + 4][p] = __builtin_elementwise_fma(ah, bp[p], acc[rr + 4][p]);
                    }
                }
            }
            __syncthreads();   // next buffer written AND current buffer drained
        }

        // ---- fold distances (k ascending -> first-min tie rule) ----
        const float4* esq4 = (const float4*)(ws + WS_ESQ + pass * 256 + tx * 16);
        float4 eqv0 = esq4[0], eqv1 = esq4[1], eqv2 = esq4[2], eqv3 = esq4[3];
        float eq[16] = {eqv0.x, eqv0.y, eqv0.z, eqv0.w, eqv1.x, eqv1.y, eqv1.z, eqv1.w,
                        eqv2.x, eqv2.y, eqv2.z, eqv2.w, eqv3.x, eqv3.y, eqv3.z, eqv3.w};
        const int kb = pass * 256 + tx * 16;
#pragma unroll
        for (int rr = 0; rr < 8; rr++)
#pragma unroll
            for (int p = 0; p < 8; p++)
#pragma unroll
                for (int e = 0; e < 2; e++) {
                    float dist = fmaf(-2.f, acc[rr][p][e], xsq[rr]) + eq[p * 2 + e];
                    if (dist < best[rr]) { best[rr] = dist; bidx[rr] = kb + p * 2 + e; }
                }
    }

    // ---- cross-tx reduce over the 16 lanes sharing rows ----
    int* sIdx = (int*)sxq;
#pragma unroll
    for (int rr = 0; rr < 8; rr++) {
        float bd = best[rr]; int bi = bidx[rr];
#pragma unroll
        for (int m = 1; m < 16; m <<= 1) {
            float od = __shfl_xor(bd, m, 64);
            int   oi = __shfl_xor(bi, m, 64);
            if (od < bd || (od == bd && oi < bi)) { bd = od; bi = oi; }
        }
        if (tx == 0) sIdx[ty * 8 + rr] = bi;
    }
    __syncthreads();   // drains sIdx writes AND this block's zero-fill stores

    // ---- tail: idx, one-hot, quantized gather, loss ----
    if (t < 128) {
        const int row = b * 128 + t;
        const int bi = sIdx[t];
        ((int*)ws)[WS_IDX + row] = bi;
        out[OUT_ENC + (size_t)row * KEMB + bi] = 1.0f;   // zero-fill drained above
        const float4* ebb = (const float4*)(E + (size_t)bi * DIM);
        const float4* xr4 = (const float4*)(x + (size_t)row * DIM);
        float4* qo = (float4*)(out + OUT_Q + (size_t)row * DIM);
        float l0 = 0.f, l1 = 0.f, l2 = 0.f, l3 = 0.f;
#pragma unroll
        for (int j = 0; j < 16; j++) {
            float4 ev = ebb[j];
            float4 xv = xr4[j];
            qo[j] = ev;
            float d0 = ev.x - xv.x, d1 = ev.y - xv.y;
            float d2 = ev.z - xv.z, d3 = ev.w - xv.w;
            l0 = fmaf(d0, d0, l0); l1 = fmaf(d1, d1, l1);
            l2 = fmaf(d2, d2, l2); l3 = fmaf(d3, d3, l3);
        }
        float lsum = (l0 + l1) + (l2 + l3);
#pragma unroll
        for (int o = 32; o; o >>= 1) lsum += __shfl_down(lsum, o, 64);
        if ((t & 63) == 0) unsafeAtomicAdd(ws + WS_LOSS, lsum);
    }
}

// K2: d-sliced dw + (d-group-0 blocks) code histogram. 512 blocks = 16
// d-groups (4 dims) x 32 row-chunks (2048 rows). tab padded to 2056 (4 dsub
// lanes hit 4 distinct banks). Flush skips exact zeros.
__global__ __launch_bounds__(256) void k2_dwD(const float* __restrict__ x,
                                              const int* __restrict__ idxp,
                                              float* __restrict__ ws) {
    __shared__ float tab[4][2056];         // 32.1 KB, padded
    __shared__ unsigned int htab[KEMB];    // 8 KB (used when b&15==0)
    const int t = threadIdx.x;
    const int b = blockIdx.x;              // 512 blocks
    const int d0 = (b & 15) * 4;
    const int rbase = (b >> 4) * 2048;
    const bool counting = (b & 15) == 0;

#pragma unroll
    for (int j = 0; j < 33; j++) {
        int p = t + j * 256;
        if (p < 4 * 2056) ((float*)tab)[p] = 0.f;
    }
    if (counting) {
#pragma unroll
        for (int j = 0; j < 8; j++) htab[t + j * 256] = 0u;
    }
    __syncthreads();

    const int rt = t >> 2;        // 0..63 (row within iteration group)
    const int dsub = t & 3;       // 0..3
#pragma unroll 8
    for (int i = 0; i < 32; i++) {
        int row = rbase + i * 64 + rt;
        int code = idxp[row];                               // 4-lane broadcast
        float v = x[(size_t)row * DIM + d0 + dsub];         // 16B/row coalesced
        atomicAdd(&tab[dsub][code], v);                     // bank-conflict-free over dsub
        if (counting && dsub == 0) atomicAdd(&htab[code], 1u);
    }
    __syncthreads();

#pragma unroll
    for (int dl = 0; dl < 4; dl++)
#pragma unroll
        for (int j2 = 0; j2 < 8; j2++) {
            int k = t + j2 * 256;
            float v = tab[dl][k];
            if (v != 0.f)
                unsafeAtomicAdd(ws + WS_DW + (size_t)(d0 + dl) * KEMB + k, v);
        }
    if (counting) {
#pragma unroll
        for (int j = 0; j < 8; j++) {
            int k = t + j * 256;
            unsigned int v = htab[k];
            if (v) atomicAdd(((unsigned int*)ws) + WS_CNT + k, v);
        }
    }
}

// K3: stats + ncs + new_embedding (reads transposed dwT). 128 blocks.
__global__ __launch_bounds__(256) void k3_se(const float* __restrict__ cs_in,
                                             const float* __restrict__ E,
                                             const float* __restrict__ ws,
                                             float* __restrict__ out) {
    __shared__ float sred[8];
    __shared__ float sscale[16];
    __shared__ float s_n;
    const int t = threadIdx.x;
    const int b = blockIdx.x;
    const unsigned int* cnt = ((const unsigned int*)ws) + WS_CNT;

    float ln = 0.f, lent = 0.f;
#pragma unroll
    for (int j = 0; j < 8; j++) {
        int k = t * 8 + j;
        float c = (float)cnt[k];
        float ncs = DECAYF * cs_in[k] + OMDF * c;
        ln += ncs;
        float p = c * (1.0f / 65536.0f);
        lent = fmaf(p, logf(p + 1e-10f), lent);
    }
#pragma unroll
    for (int o = 32; o; o >>= 1) {
        ln += __shfl_down(ln, o, 64);
        lent += __shfl_down(lent, o, 64);
    }
    if ((t & 63) == 0) { sred[t >> 6] = ln; sred[4 + (t >> 6)] = lent; }
    __syncthreads();
    if (t == 0) {
        float n = (sred[0] + sred[1]) + (sred[2] + sred[3]);
        float ent = (sred[4] + sred[5]) + (sred[6] + sred[7]);
        s_n = n;
        if (b == 0) {
            out[OUT_LOSS] = ws[WS_LOSS] * (1.0f / 4194304.0f);
            out[OUT_PERP] = expf(-ent);
        }
    }
    __syncthreads();
    const float n = s_n;

    if (t < 16) {
        int k = b * 16 + t;
        float c = (float)cnt[k];
        float ncs = DECAYF * cs_in[k] + OMDF * c;
        out[OUT_NCS + k] = ncs;
        float cs = (ncs + EPSF) / (n + (float)KEMB * EPSF) * n;
        sscale[t] = OMDF / cs;
    }
    __syncthreads();

    // NE: thread owns code kk = b*16 + (t&15), dims d4*4..d4*4+3 (d4 = t>>4).
    const int kk = b * 16 + (t & 15);
    const int d4 = t >> 4;
    const float sc = sscale[t & 15];
    float dv0 = ws[WS_DW + (size_t)(d4 * 4 + 0) * KEMB + kk];
    float dv1 = ws[WS_DW + (size_t)(d4 * 4 + 1) * KEMB + kk];
    float dv2 = ws[WS_DW + (size_t)(d4 * 4 + 2) * KEMB + kk];
    float dv3 = ws[WS_DW + (size_t)(d4 * 4 + 3) * KEMB + kk];
    float4 e = ((const float4*)E)[kk * 16 + d4];
    float2 r0, r1;
    r0.x = fmaf(dv0, sc, DECAYF * e.x);
    r0.y = fmaf(dv1, sc, DECAYF * e.y);
    r1.x = fmaf(dv2, sc, DECAYF * e.z);
    r1.y = fmaf(dv3, sc, DECAYF * e.w);
    float2* o2 = (float2*)(out + OUT_NE);
    o2[(kk * 64 + d4 * 4) / 2 + 0] = r0;
    o2[(kk * 64 + d4 * 4) / 2 + 1] = r1;
}

extern "C" void kernel_launch(void* const* d_in, const int* in_sizes, int n_in,
                              void* d_out, int out_size, void* d_ws, size_t ws_size,
                              hipStream_t stream) {
    const float* x = (const float*)d_in[0];
    const float* E = (const float*)d_in[1];
    const float* cs = (const float*)d_in[2];
    float* out = (float*)d_out;
    float* ws = (float*)d_ws;
    const int* idxp = ((const int*)ws) + WS_IDX;

    hipLaunchKernelGGL(k0_prep, dim3(128), dim3(256), 0, stream, E, ws);
    hipLaunchKernelGGL(k1_main, dim3(512), dim3(256), 0, stream, x, E, ws, out);
    hipLaunchKernelGGL(k2_dwD, dim3(512), dim3(256), 0, stream, x, idxp, ws);
    hipLaunchKernelGGL(k3_se, dim3(128), dim3(256), 0, stream, cs, E, ws, out);
}